// Round 19
// baseline (482.242 us; speedup 1.0000x reference)
//
#include <hip/hip_runtime.h>

// ABLATION ROUND 2 — ×4-scaled probes so every variant clears the 40 µs
// fillBuffer floor in the top-5 table. V0 (real, grid 31,8,32) + probes at
// (31,8,128) [n=z&31]: V3=loads, V1=+stage+barrier+dsread, V2=+bfrags+MFMA+max,
// V0d=full->scratch. V4=empty at (31,8,512) for the dispatch floor.
// Keepalives per rule #17. Read: equiv = dur/4 (V4: /16).

using f32x16 = __attribute__((ext_vector_type(16))) float;
using bf16x8 = __attribute__((ext_vector_type(8))) short;
using s16x4  = __attribute__((ext_vector_type(4))) short;

__device__ inline unsigned short f2bf(float f) {
  unsigned int u = __float_as_uint(f);
  unsigned int r = 0x7fffu + ((u >> 16) & 1u);
  return (unsigned short)((u + r) >> 16);
}

#define WS_FRAG_OFF    32768   // u32 units: frags at byte 128 KB
#define WS_SCRATCH_OFF 40960   // float units: scratch at byte 160 KB (+32 KB)

__global__ void prep_bfrags(const float* __restrict__ wgt, float* __restrict__ ws)
{
  int idx = blockIdx.x*256 + threadIdx.x;
  if (idx >= 1152) return;
  short* fb = (short*)((unsigned int*)ws + WS_FRAG_OFF);
  int l = idx & 63, rest = idx >> 6;
  int kw = rest % 3, kc = (rest/3) % 3, dd = rest/9;
  int col = l & 31, half = l >> 5;
  int ch = col & 15, hh = col >> 4;
  short f[8];
  #pragma unroll
  for (int j = 0; j < 8; ++j) {
    int kloc = half*8 + j;
    int drel = kloc >> 2, h = kloc & 3;
    int kd = drel - dd, kh = h - hh;
    bool ok = (kd >= 0) && (kd < 3) && (kh >= 0) && (kh < 3);
    float v = ok ? wgt[ch*81 + kc*27 + kd*9 + kh*3 + kw] : 0.f;
    f[j] = (short)f2bf(v);
  }
  bf16x8 q = { f[0], f[1], f[2], f[3], f[4], f[5], f[6], f[7] };
  *reinterpret_cast<bf16x8*>(&fb[idx*8]) = q;
}

// V: 0=real(ws partials) 10=full->scratch 2=noReduce 1=loads+stage+dsread
//    3=loads only 4=empty
template<int V>
__global__ __launch_bounds__(256, 2) void probe_kernel(
    const float* __restrict__ x, const float* __restrict__ ws_in,
    float* __restrict__ ws)
{
  __shared__ __align__(16) unsigned short xt[2][66*64];

  const int tid = threadIdx.x;
  const int ph  = blockIdx.x;
  const int pdg = blockIdx.y;
  const int nz  = blockIdx.z;
  const int n   = nz & 31;
  const int l   = tid & 63;
  const int wid = tid >> 6;
  const int p = wid >> 1, mtile = wid & 1;
  const int half = l >> 5;
  const int w = l, kq = wid;
  float* scratch = ws + WS_SCRATCH_OFF;
  const int bflat = (n*8 + pdg)*31 + ph;

  if constexpr (V == 4) {
    if (nz < 32 && tid == 0) scratch[bflat] = 1.0f;
    return;
  }

  // ---- phase L: 18 global dword loads (v8 pattern)
  const float* xn = x + (size_t)n*(3*32*64*64);
  const int D0 = 4*pdg, H0 = 2*ph;
  float pf[5][4];
  #pragma unroll
  for (int j = 0; j < 5; ++j) {
    int g = kq + 4*j;
    if (g >= 18) break;
    int ci = g / 6, s = g - 6*ci;
    int d  = D0 + s; d = (d < 32) ? d : 31;
    const float* xp = xn + (size_t)(ci*32 + d)*4096 + H0*64 + w;
    #pragma unroll
    for (int h = 0; h < 4; ++h) pf[j][h] = xp[h*64];
  }

  if constexpr (V == 3) {
    #pragma unroll
    for (int j = 0; j < 5; ++j)
      asm volatile("" :: "v"(pf[j][0]), "v"(pf[j][1]),
                        "v"(pf[j][2]), "v"(pf[j][3]));
    if (tid == 0) scratch[bflat] = 2.0f;
    return;
  }

  // ---- phase S: f2bf + swizzled ds_write + barrier
  #pragma unroll
  for (int j = 0; j < 5; ++j) {
    int g = kq + 4*j;
    if (g >= 18) break;
    int ci = g / 6, s = g - 6*ci;
    s16x4 v = { (short)f2bf(pf[j][0]), (short)f2bf(pf[j][1]),
                (short)f2bf(pf[j][2]), (short)f2bf(pf[j][3]) };
    if (s < 4) {
      int off = (ci*16 + s*4) ^ ((w & 7) << 3);
      *reinterpret_cast<s16x4*>(&xt[0][w*64 + off]) = v;
    }
    if (s >= 2) {
      int off = (ci*16 + (s - 2)*4) ^ ((w & 7) << 3);
      *reinterpret_cast<s16x4*>(&xt[1][w*64 + off]) = v;
    }
  }
  __syncthreads();

  // ---- phase R: A-frag ds_reads
  const int rowbase = mtile*32 + (l & 31);
  bf16x8 af[3][3];
  #pragma unroll
  for (int kc = 0; kc < 3; ++kc) {
    #pragma unroll
    for (int kw = 0; kw < 3; ++kw) {
      int row = rowbase + kw;
      int off = ((kc*2 + half)*8) ^ ((row & 7) << 3);
      af[kc][kw] = *reinterpret_cast<const bf16x8*>(&xt[p][row*64 + off]);
    }
  }

  if constexpr (V == 1) {
    #pragma unroll
    for (int kc = 0; kc < 3; ++kc)
      #pragma unroll
      for (int kw = 0; kw < 3; ++kw)
        asm volatile("" :: "v"(af[kc][kw]));
    if (tid == 0) scratch[bflat] = 3.0f;
    return;
  }

  // ---- phase M: B-frag loads + 18 MFMA + window maxes (incl. hh shfl_xor)
  const short* fb = (const short*)((const unsigned int*)ws_in + WS_FRAG_OFF);
  float pv[8];
  #pragma unroll
  for (int jj = 0; jj < 8; ++jj) pv[jj] = -3.4e38f;
  #pragma unroll
  for (int dd = 0; dd < 2; ++dd) {
    bf16x8 bfr[3][3];
    #pragma unroll
    for (int kc = 0; kc < 3; ++kc)
      #pragma unroll
      for (int kw = 0; kw < 3; ++kw)
        bfr[kc][kw] = *reinterpret_cast<const bf16x8*>(
            &fb[(((dd*3 + kc)*3 + kw)*64 + l)*8]);
    f32x16 acc = {0.f,0.f,0.f,0.f,0.f,0.f,0.f,0.f,
                  0.f,0.f,0.f,0.f,0.f,0.f,0.f,0.f};
    #pragma unroll
    for (int kc = 0; kc < 3; ++kc)
      #pragma unroll
      for (int kw = 0; kw < 3; ++kw)
        acc = __builtin_amdgcn_mfma_f32_32x32x16_bf16(af[kc][kw], bfr[kc][kw],
                                                      acc, 0, 0, 0);
    #pragma unroll
    for (int jj = 0; jj < 8; ++jj)
      pv[jj] = fmaxf(pv[jj], fmaxf(acc[2*jj], acc[2*jj + 1]));
  }
  #pragma unroll
  for (int jj = 0; jj < 8; ++jj)
    pv[jj] = fmaxf(pv[jj], __shfl_xor(pv[jj], 16, 64));
  if (mtile && half) pv[7] = 0.f;
  float S = 0.f;
  #pragma unroll
  for (int jj = 0; jj < 8; ++jj) S += pv[jj];
  if (l & 16) S = 0.f;
  if (pdg == 7 && p == 1) S = 0.f;

  if constexpr (V == 2) {           // stop before serial reduce chain
    asm volatile("" :: "v"(S));
    if (tid == 0) scratch[bflat] = 4.0f;
    return;
  }

  // ---- phase E: serial shuffle reduce + store
  #pragma unroll
  for (int off = 32; off > 0; off >>= 1) S += __shfl_down(S, off, 64);
  if constexpr (V == 10) {
    if (l == 0) scratch[bflat] = S;
    return;
  }
  if (l == 0)
    ws[n*1024 + (pdg*31 + ph)*4 + wid] = S;
}

__global__ void finalize_kernel(const float* __restrict__ ws,
                                const float* __restrict__ cb,
                                const float* __restrict__ bias,
                                float* __restrict__ out)
{
  const int n = blockIdx.x, l = threadIdx.x;
  float t = 0.f;
  #pragma unroll
  for (int r = 0; r < 16; ++r) {
    int s = l + r*64;
    if (s < 992) t += ws[n*1024 + s];
  }
  #pragma unroll
  for (int off = 32; off > 0; off >>= 1) t += __shfl_down(t, off, 64);
  if (l == 0) {
    float C = 0.f;
    #pragma unroll
    for (int c = 0; c < 16; ++c) C += cb[c]*0.5f + bias[c];
    out[n] = t * (1.0f/(2.0f*14415.0f)) + C;
  }
}

extern "C" void kernel_launch(void* const* d_in, const int* in_sizes, int n_in,
                              void* d_out, int out_size, void* d_ws, size_t ws_size,
                              hipStream_t stream) {
  (void)in_sizes; (void)n_in; (void)out_size; (void)ws_size;
  const float* x    = (const float*)d_in[0];
  const float* wgt  = (const float*)d_in[1];
  const float* cb   = (const float*)d_in[2];
  const float* bias = (const float*)d_in[3];
  float* out = (float*)d_out;
  float* ws  = (float*)d_ws;

  prep_bfrags<<<5, 256, 0, stream>>>(wgt, ws);
  dim3 g1(31, 8, 32);            // real
  dim3 g4(31, 8, 128);           // x4 probes
  dim3 g16(31, 8, 512);          // x16 dispatch floor
  probe_kernel<0 ><<<g1,  256, 0, stream>>>(x, ws, ws);
  probe_kernel<4 ><<<g16, 256, 0, stream>>>(x, ws, ws);
  probe_kernel<3 ><<<g4,  256, 0, stream>>>(x, ws, ws);
  probe_kernel<1 ><<<g4,  256, 0, stream>>>(x, ws, ws);
  probe_kernel<2 ><<<g4,  256, 0, stream>>>(x, ws, ws);
  probe_kernel<10><<<g4,  256, 0, stream>>>(x, ws, ws);
  finalize_kernel<<<32, 64, 0, stream>>>(ws, cb, bias, out);
}

// Round 20
// 49.337 us; speedup vs baseline: 9.7744x; 9.7744x over previous
//
#include <hip/hip_runtime.h>

// Implicit-GEMM MFMA v11 — long-lived blocks: block=(ph,n)=992, loop pdg=0..7,
// v8 inner body, next-iteration global loads issued under current MFMA phase.
// Conv3d(3->16,k3,valid)+bias, /2, MaxPool3d(2), GlobalAvgPool, +bias, channel-sum.
// out[n] = (1/(2*14415)) * sum_{c,windows} max_window(conv_c) + sum_c(cb_c/2 + bias_c)
//
// Per iter: pd pair = (2pdg, 2pdg+1). LDS xt[p][w][k], k=ci*16+drel*4+h (48
// real), bf16, 16B-slot XOR swizzle (w&7). Waves=(p,mtile); A-frags in regs
// reused across dd; dd-max in-register. B[k][col] frags precomputed in ws.
// C: col=lane&31, row=(reg&3)+8*(reg>>2)+4*(lane>>5). Exclusions: pw=31,
// l&16 dup, ragged pd (pdg=7,p=1).

using f32x16 = __attribute__((ext_vector_type(16))) float;
using bf16x8 = __attribute__((ext_vector_type(8))) short;
using s16x4  = __attribute__((ext_vector_type(4))) short;

__device__ inline unsigned short f2bf(float f) {
  unsigned int u = __float_as_uint(f);
  unsigned int r = 0x7fffu + ((u >> 16) & 1u);   // RNE for finite inputs
  return (unsigned short)((u + r) >> 16);
}

#define WS_FRAG_OFF 32768   // u32 units: frags at byte 128 KB (partials 0..128 KB)

__global__ void prep_bfrags(const float* __restrict__ wgt, float* __restrict__ ws)
{
  int idx = blockIdx.x*256 + threadIdx.x;
  if (idx >= 1152) return;
  short* fb = (short*)((unsigned int*)ws + WS_FRAG_OFF);
  int l = idx & 63, rest = idx >> 6;
  int kw = rest % 3, kc = (rest/3) % 3, dd = rest/9;
  int col = l & 31, half = l >> 5;
  int ch = col & 15, hh = col >> 4;
  short f[8];
  #pragma unroll
  for (int j = 0; j < 8; ++j) {
    int kloc = half*8 + j;
    int drel = kloc >> 2, h = kloc & 3;
    int kd = drel - dd, kh = h - hh;
    bool ok = (kd >= 0) && (kd < 3) && (kh >= 0) && (kh < 3);
    float v = ok ? wgt[ch*81 + kc*27 + kd*9 + kh*3 + kw] : 0.f;
    f[j] = (short)f2bf(v);
  }
  bf16x8 q = { f[0], f[1], f[2], f[3], f[4], f[5], f[6], f[7] };
  *reinterpret_cast<bf16x8*>(&fb[idx*8]) = q;
}

// issue pdg PD's 18 slice loads into PF registers
#define ISSUE(PF, PD) do {                                                  \
    int D0_ = 4*(PD);                                                       \
    _Pragma("unroll")                                                       \
    for (int j = 0; j < 5; ++j) {                                           \
      int g = kq + 4*j;                                                     \
      if (g < 18) {                                                         \
        int ci = g / 6, s = g - 6*(g/6);                                    \
        int d = D0_ + s; d = (d < 32) ? d : 31;                             \
        const float* xp = xn + (size_t)(ci*32 + d)*4096 + H0*64 + l;        \
        _Pragma("unroll")                                                   \
        for (int h = 0; h < 4; ++h) PF[j][h] = xp[h*64];                    \
      }                                                                     \
    }                                                                       \
  } while (0)

// consume PF -> f2bf + swizzled ds_writes (layout independent of pdg)
#define STAGE(PF) do {                                                      \
    _Pragma("unroll")                                                       \
    for (int j = 0; j < 5; ++j) {                                           \
      int g = kq + 4*j;                                                     \
      if (g < 18) {                                                         \
        int ci = g / 6, s = g - 6*(g/6);                                    \
        s16x4 v = { (short)f2bf(PF[j][0]), (short)f2bf(PF[j][1]),           \
                    (short)f2bf(PF[j][2]), (short)f2bf(PF[j][3]) };         \
        if (s < 4) {                                                        \
          int off = (ci*16 + s*4) ^ ((l & 7) << 3);                         \
          *reinterpret_cast<s16x4*>(&xt[0][l*64 + off]) = v;                \
        }                                                                   \
        if (s >= 2) {                                                       \
          int off = (ci*16 + (s - 2)*4) ^ ((l & 7) << 3);                   \
          *reinterpret_cast<s16x4*>(&xt[1][l*64 + off]) = v;                \
        }                                                                   \
      }                                                                     \
    }                                                                       \
  } while (0)

__global__ __launch_bounds__(256, 2) void conv_mfma_kernel(
    const float* __restrict__ x, const float* __restrict__ ws_in,
    float* __restrict__ ws)
{
  __shared__ __align__(16) unsigned short xt[2][66*64];  // 16,896 B, swizzled

  const int tid = threadIdx.x;
  const int ph  = blockIdx.x;       // 0..30
  const int n   = blockIdx.y;       // 0..31
  const int l   = tid & 63;
  const int wid = tid >> 6;
  const int p = wid >> 1, mtile = wid & 1;
  const int half = l >> 5;
  const int kq = wid;

  const float* xn = x + (size_t)n*(3*32*64*64);
  const int H0 = 2*ph;
  const short* fb = (const short*)((const unsigned int*)ws_in + WS_FRAG_OFF);
  const int rowbase = mtile*32 + (l & 31);

  float pf[5][4];
  ISSUE(pf, 0);                     // prologue prefetch

  #pragma unroll 1
  for (int pdg = 0; pdg < 8; ++pdg) {
    STAGE(pf);                      // waits pf, writes xt
    __syncthreads();                // xt ready

    // A-frags (9 ds_read_b128), reused for both dd
    bf16x8 af[3][3];
    #pragma unroll
    for (int kc = 0; kc < 3; ++kc) {
      #pragma unroll
      for (int kw = 0; kw < 3; ++kw) {
        int row = rowbase + kw;
        int off = ((kc*2 + half)*8) ^ ((row & 7) << 3);
        af[kc][kw] = *reinterpret_cast<const bf16x8*>(&xt[p][row*64 + off]);
      }
    }

    if (pdg < 7) ISSUE(pf, pdg + 1);   // fire next loads under MFMA phase

    float pv[8];
    #pragma unroll
    for (int jj = 0; jj < 8; ++jj) pv[jj] = -3.4e38f;
    #pragma unroll
    for (int dd = 0; dd < 2; ++dd) {
      bf16x8 bfr[3][3];
      #pragma unroll
      for (int kc = 0; kc < 3; ++kc)
        #pragma unroll
        for (int kw = 0; kw < 3; ++kw)
          bfr[kc][kw] = *reinterpret_cast<const bf16x8*>(
              &fb[(((dd*3 + kc)*3 + kw)*64 + l)*8]);
      f32x16 acc = {0.f,0.f,0.f,0.f,0.f,0.f,0.f,0.f,
                    0.f,0.f,0.f,0.f,0.f,0.f,0.f,0.f};
      #pragma unroll
      for (int kc = 0; kc < 3; ++kc)
        #pragma unroll
        for (int kw = 0; kw < 3; ++kw)
          acc = __builtin_amdgcn_mfma_f32_32x32x16_bf16(af[kc][kw], bfr[kc][kw],
                                                        acc, 0, 0, 0);
      #pragma unroll
      for (int jj = 0; jj < 8; ++jj)
        pv[jj] = fmaxf(pv[jj], fmaxf(acc[2*jj], acc[2*jj + 1]));
    }

    // hh-max, exclusions, wave sum, store partial
    #pragma unroll
    for (int jj = 0; jj < 8; ++jj)
      pv[jj] = fmaxf(pv[jj], __shfl_xor(pv[jj], 16, 64));
    if (mtile && half) pv[7] = 0.f;        // pw == 31
    float S = 0.f;
    #pragma unroll
    for (int jj = 0; jj < 8; ++jj) S += pv[jj];
    if (l & 16) S = 0.f;                   // hh duplicate lanes
    if (pdg == 7 && p == 1) S = 0.f;       // ragged pd
    #pragma unroll
    for (int off = 32; off > 0; off >>= 1) S += __shfl_down(S, off, 64);
    if (l == 0)
      ws[n*1024 + (pdg*31 + ph)*4 + wid] = S;   // 992 slots/n

    __syncthreads();                // xt reusable next iter
  }
}

// ---- finalize: one block per n, 64 lanes stride the 992 partials.
__global__ void finalize_kernel(const float* __restrict__ ws,
                                const float* __restrict__ cb,
                                const float* __restrict__ bias,
                                float* __restrict__ out)
{
  const int n = blockIdx.x, l = threadIdx.x;
  float t = 0.f;
  #pragma unroll
  for (int r = 0; r < 16; ++r) {
    int s = l + r*64;
    if (s < 992) t += ws[n*1024 + s];
  }
  #pragma unroll
  for (int off = 32; off > 0; off >>= 1) t += __shfl_down(t, off, 64);
  if (l == 0) {
    float C = 0.f;
    #pragma unroll
    for (int c = 0; c < 16; ++c) C += cb[c]*0.5f + bias[c];
    out[n] = t * (1.0f/(2.0f*14415.0f)) + C;
  }
}

extern "C" void kernel_launch(void* const* d_in, const int* in_sizes, int n_in,
                              void* d_out, int out_size, void* d_ws, size_t ws_size,
                              hipStream_t stream) {
  (void)in_sizes; (void)n_in; (void)out_size; (void)ws_size;
  const float* x    = (const float*)d_in[0];
  const float* wgt  = (const float*)d_in[1];
  const float* cb   = (const float*)d_in[2];
  const float* bias = (const float*)d_in[3];
  float* out = (float*)d_out;
  float* ws  = (float*)d_ws;     // partials 128 KB @0; frags 18.4 KB @128 KB

  prep_bfrags<<<5, 256, 0, stream>>>(wgt, ws);
  dim3 grid(31, 32);             // (ph, n) = 992 blocks
  conv_mfma_kernel<<<grid, 256, 0, stream>>>(x, ws, ws);
  finalize_kernel<<<32, 64, 0, stream>>>(ws, cb, bias, out);
}